// Round 6
// baseline (243.483 us; speedup 1.0000x reference)
//
#include <hip/hip_runtime.h>
#include <hip/hip_bf16.h>
#include <stdint.h>

#define D_DIM 128
#define L_REL 32
#define AGG_LDW 132   // f32 dword stride, agg tile
#define MSG_LDW 132   // ushort stride, msg transpose tile (264B rows)

typedef __attribute__((ext_vector_type(8))) short short8;   // 8 bf16 = 4 VGPR
typedef __attribute__((ext_vector_type(4))) float f32x4;    // MFMA accumulator

__device__ __forceinline__ unsigned short f2bf(float f) {
    union { float f; unsigned u; } v; v.f = f;
    unsigned r = v.u + 0x7FFFu + ((v.u >> 16) & 1u);   // round-to-nearest-even
    return (unsigned short)(r >> 16);
}
__device__ __forceinline__ float bf_lo(unsigned m) { return __uint_as_float(m << 16); }
__device__ __forceinline__ float bf_hi(unsigned m) { return __uint_as_float(m & 0xffff0000u); }

// B-operand fragment: lane holds W[k][c] for c = tile*16 + (lane&15),
// k = kk*32 + (lane>>4)*8 + j (j contiguous).
__device__ __forceinline__ void load_wfrag(const float* __restrict__ Wr,
                                           int w, int l15, int lq,
                                           short8 wf[2][4]) {
#pragma unroll
    for (int n = 0; n < 2; ++n) {
        int c = (w * 2 + n) * 16 + l15;
#pragma unroll
        for (int kk = 0; kk < 4; ++kk) {
            int kb = kk * 32 + lq * 8;
            short8 f;
#pragma unroll
            for (int j = 0; j < 8; ++j)
                f[j] = (short)f2bf(Wr[(size_t)(kb + j) * D_DIM + c]);
            wf[n][kk] = f;
        }
    }
}

// 64x128 (rows x k, bf16, XOR-swizzled) LDS tile  @  W(128x128) -> acc 64x128
__device__ __forceinline__ void mfma_tile(const unsigned short* xs,
                                          const short8 wf[2][4],
                                          int l15, int lq, f32x4 acc[4][2]) {
#pragma unroll
    for (int kk = 0; kk < 4; ++kk) {
        short8 a[4];
#pragma unroll
        for (int m = 0; m < 4; ++m) {
            int row = m * 16 + l15;
            unsigned byte = ((unsigned)(row * 256 + (kk * 32 + lq * 8) * 2))
                          ^ (((unsigned)(row & 7)) << 4);
            a[m] = *reinterpret_cast<const short8*>(
                       reinterpret_cast<const char*>(xs) + byte);
        }
#pragma unroll
        for (int m = 0; m < 4; ++m)
#pragma unroll
            for (int n = 0; n < 2; ++n)
                acc[m][n] = __builtin_amdgcn_mfma_f32_16x16x32_bf16(
                                a[m], wf[n][kk], acc[m][n], 0, 0, 0);
    }
}

// ===================== combined CSR build (deg = in-deg fwd+rev) ===========
__global__ void hist_kernel(const int* __restrict__ dep, const int* __restrict__ gov,
                            int* __restrict__ deg, int E) {
    int i = blockIdx.x * blockDim.x + threadIdx.x;
    int stride = gridDim.x * blockDim.x;
    for (; i < E; i += stride) {
        atomicAdd(&deg[dep[i]], 1);
        atomicAdd(&deg[gov[i]], 1);
    }
}

__global__ __launch_bounds__(256) void scanA_kernel(const int* __restrict__ deg,
                                                    int* __restrict__ off,
                                                    int* __restrict__ partials) {
    __shared__ int ls[256];
    const int tid = threadIdx.x;
    const int gi = blockIdx.x * 256 + tid;
    int4 v = ((const int4*)deg)[gi];
    int s = v.x + v.y + v.z + v.w;
    ls[tid] = s;
    __syncthreads();
    for (int o = 1; o < 256; o <<= 1) {
        int t = (tid >= o) ? ls[tid - o] : 0;
        __syncthreads();
        ls[tid] += t;
        __syncthreads();
    }
    int e0 = ls[tid] - s;
    int4 e; e.x = e0; e.y = e0 + v.x; e.z = e.y + v.y; e.w = e.z + v.z;
    ((int4*)off)[gi] = e;
    if (tid == 255) partials[blockIdx.x] = ls[255];
}

__global__ __launch_bounds__(256) void scanB_kernel(int* __restrict__ partials) {
    __shared__ int ls[256];
    const int tid = threadIdx.x;
    int v = partials[tid];
    ls[tid] = v;
    __syncthreads();
    for (int o = 1; o < 256; o <<= 1) {
        int t = (tid >= o) ? ls[tid - o] : 0;
        __syncthreads();
        ls[tid] += t;
        __syncthreads();
    }
    partials[tid] = ls[tid] - v;   // exclusive
}

__global__ __launch_bounds__(256) void scanC_kernel(int* __restrict__ off,
                                                    int* __restrict__ cur,
                                                    const int* __restrict__ partials) {
    const int p = partials[blockIdx.x];
    const int gi = blockIdx.x * 256 + threadIdx.x;
    int4 v = ((int4*)off)[gi];
    v.x += p; v.y += p; v.z += p; v.w += p;
    ((int4*)off)[gi] = v;
    ((int4*)cur)[gi] = v;
}

// ====================== messages -> dst-sorted bf16 buffer ==================
#define CPB 2
__global__ __launch_bounds__(256) void msg_kernel(const float* __restrict__ x,
                                                  const float* __restrict__ W,
                                                  const float* __restrict__ b,
                                                  const int* __restrict__ dep,
                                                  const int* __restrict__ gov,
                                                  int* __restrict__ cur,
                                                  unsigned* __restrict__ msg,
                                                  int eg, int blocksPerRel) {
    // union: xs (64x128 bf16 swizzled, 16KB) / tr (64x132 ushort, 16.9KB)
    __shared__ __align__(16) char smem[64 * MSG_LDW * 2];
    unsigned short* xs = (unsigned short*)smem;
    unsigned short* tr = (unsigned short*)smem;
    __shared__ int sidx[CPB][64];
    __shared__ int didx[CPB][64];
    __shared__ int pos[64];

    const int tid = threadIdx.x;
    const int lane = tid & 63, w = tid >> 6;
    const int l15 = lane & 15, lq = lane >> 4;

    const int bid = blockIdx.x;
    const int vr = bid / blocksPerRel;
    const int blk = bid % blocksPerRel;
    const int r = vr & 31;
    const bool fwd = (vr < 32);
    const int* __restrict__ srcI = fwd ? gov : dep;
    const int* __restrict__ dstI = fwd ? dep : gov;

    const int ebase0 = r * eg + blk * CPB * 64;
    if (tid < CPB * 64) {
        int c = tid >> 6, t = tid & 63;
        sidx[c][t] = srcI[ebase0 + c * 64 + t];
        didx[c][t] = dstI[ebase0 + c * 64 + t];
    }

    short8 wf[2][4];
    load_wfrag(W + (size_t)(2 + vr) * D_DIM * D_DIM, w, l15, lq, wf);
    float bias[2];
#pragma unroll
    for (int n = 0; n < 2; ++n)
        bias[n] = b[(size_t)(2 + vr) * D_DIM + (w * 2 + n) * 16 + l15];

    __syncthreads();

    for (int ch = 0; ch < CPB; ++ch) {
        // gather 64 source rows -> bf16 swizzled LDS
#pragma unroll
        for (int it = 0; it < 8; ++it) {
            int flat = it * 256 + tid;
            int row = flat >> 5, f4 = flat & 31;
            float4 v = *reinterpret_cast<const float4*>(
                           x + (size_t)sidx[ch][row] * D_DIM + f4 * 4);
            unsigned lo = (unsigned)f2bf(v.x) | ((unsigned)f2bf(v.y) << 16);
            unsigned hi = (unsigned)f2bf(v.z) | ((unsigned)f2bf(v.w) << 16);
            unsigned byte = ((unsigned)(row * 256 + f4 * 8))
                          ^ (((unsigned)(row & 7)) << 4);
            *reinterpret_cast<uint2*>(reinterpret_cast<char*>(xs) + byte) =
                make_uint2(lo, hi);
        }
        __syncthreads();

        f32x4 acc[4][2];
#pragma unroll
        for (int m = 0; m < 4; ++m)
#pragma unroll
            for (int n = 0; n < 2; ++n) acc[m][n] = (f32x4){0.f, 0.f, 0.f, 0.f};
        mfma_tile(xs, wf, l15, lq, acc);

        // reserve dst-sorted slots: ONE int atomic per edge (combined cur)
        if (tid < 64) pos[tid] = atomicAdd(&cur[didx[ch][tid]], 1);
        __syncthreads();   // all xs reads done; pos visible

        // transpose acc (+bias) -> bf16 LDS tile [64][MSG_LDW]
#pragma unroll
        for (int m = 0; m < 4; ++m)
#pragma unroll
            for (int reg = 0; reg < 4; ++reg) {
                int row = m * 16 + lq * 4 + reg;
#pragma unroll
                for (int n = 0; n < 2; ++n)
                    tr[row * MSG_LDW + w * 32 + n * 16 + l15] =
                        f2bf(acc[m][n][reg] + bias[n]);
            }
        __syncthreads();

        // wave-per-row: read packed dword (2 cols), store 256B row at slot
#pragma unroll
        for (int i = 0; i < 16; ++i) {
            int r0 = w * 16 + i;
            unsigned dw = *reinterpret_cast<const unsigned*>(
                              reinterpret_cast<const char*>(tr)
                              + r0 * MSG_LDW * 2 + lane * 4);
            msg[(size_t)pos[r0] * 64 + lane] = dw;
        }
        __syncthreads();
    }
}

// ====== fused: self-GEMM + monotone streaming msg reduce + bias + ReLU =====
// wave w owns nodes [w*16, w*16+16): its msg rows are CONTIGUOUS; row->node
// is a monotone pointer advance (no search, no LDS atomics); node complete ->
// self(LDS) + accm, ReLU, store direct to out.
__global__ __launch_bounds__(256) void agg_kernel(const float* __restrict__ x,
                                                  const float* __restrict__ W,
                                                  const float* __restrict__ b,
                                                  const int* __restrict__ off,
                                                  const int* __restrict__ deg,
                                                  const unsigned* __restrict__ msg,
                                                  float* __restrict__ out) {
    // union: xs (16KB) -> agg f32 (64 x AGG_LDW, 33.8KB)
    __shared__ __align__(16) char smem[64 * AGG_LDW * 4];
    unsigned short* xs = (unsigned short*)smem;
    float* agg = (float*)smem;
    __shared__ int offs[64 + 1];   // offs[64] = end of block's row range

    const int tid = threadIdx.x;
    const int lane = tid & 63, w = tid >> 6;
    const int l15 = lane & 15, lq = lane >> 4;
    const int base = blockIdx.x * 64;

    if (tid < 64) offs[tid] = off[base + tid];
    if (tid == 64) offs[64] = off[base + 63] + deg[base + 63];

    short8 wf[2][4];
    load_wfrag(W, w, l15, lq, wf);          // W[SELF]
    float bias[2];
#pragma unroll
    for (int n = 0; n < 2; ++n) bias[n] = b[(w * 2 + n) * 16 + l15];

    // stage 64 consecutive node rows
#pragma unroll
    for (int it = 0; it < 8; ++it) {
        int flat = it * 256 + tid;
        int row = flat >> 5, f4 = flat & 31;
        float4 v = *reinterpret_cast<const float4*>(
                       x + (size_t)(base + row) * D_DIM + f4 * 4);
        unsigned lo = (unsigned)f2bf(v.x) | ((unsigned)f2bf(v.y) << 16);
        unsigned hi = (unsigned)f2bf(v.z) | ((unsigned)f2bf(v.w) << 16);
        unsigned byte = ((unsigned)(row * 256 + f4 * 8))
                      ^ (((unsigned)(row & 7)) << 4);
        *reinterpret_cast<uint2*>(reinterpret_cast<char*>(xs) + byte) =
            make_uint2(lo, hi);
    }
    __syncthreads();

    f32x4 acc[4][2];
#pragma unroll
    for (int m = 0; m < 4; ++m)
#pragma unroll
        for (int n = 0; n < 2; ++n) acc[m][n] = (f32x4){0.f, 0.f, 0.f, 0.f};
    mfma_tile(xs, wf, l15, lq, acc);
    __syncthreads();   // xs consumed; LDS becomes f32 agg tile

    // seed agg with self-term (+bias)
#pragma unroll
    for (int m = 0; m < 4; ++m)
#pragma unroll
        for (int reg = 0; reg < 4; ++reg) {
            int row = m * 16 + lq * 4 + reg;
#pragma unroll
            for (int n = 0; n < 2; ++n)
                agg[row * AGG_LDW + w * 32 + n * 16 + l15] =
                    acc[m][n][reg] + bias[n];
        }
    __syncthreads();

    // ---- monotone stream over this wave's contiguous rows ----
    const int nfirst = w * 16;
    int ci = 0;                      // node cursor within wave's 16
    float2 accm = make_float2(0.f, 0.f);

#define FLUSH_NODE()                                                          \
    do {                                                                      \
        const float2 sv = *reinterpret_cast<const float2*>(                   \
            &agg[(nfirst + ci) * AGG_LDW + lane * 2]);                        \
        float2 so;                                                            \
        so.x = fmaxf(sv.x + accm.x, 0.f);                                     \
        so.y = fmaxf(sv.y + accm.y, 0.f);                                     \
        *reinterpret_cast<float2*>(                                           \
            out + (size_t)(base + nfirst + ci) * D_DIM + lane * 2) = so;      \
        accm.x = 0.f; accm.y = 0.f;                                           \
        ++ci;                                                                 \
    } while (0)

    const int s0 = offs[nfirst];
    const int s1 = offs[nfirst + 16];
    int nb = offs[nfirst + 1];
    int j = s0;
    const unsigned* mp = msg + (size_t)j * 64 + lane;

    // 4 rows in flight
    for (; j + 4 <= s1; j += 4, mp += 256) {
        unsigned v0 = mp[0];
        unsigned v1 = mp[64];
        unsigned v2 = mp[128];
        unsigned v3 = mp[192];
#pragma unroll
        for (int k = 0; k < 4; ++k) {
            unsigned v = (k == 0) ? v0 : (k == 1) ? v1 : (k == 2) ? v2 : v3;
            int jj = j + k;
            while (jj >= nb) { FLUSH_NODE(); nb = offs[nfirst + ci + 1]; }
            accm.x += bf_lo(v); accm.y += bf_hi(v);
        }
    }
    for (; j < s1; ++j, mp += 64) {
        unsigned v = mp[0];
        while (j >= nb) { FLUSH_NODE(); nb = offs[nfirst + ci + 1]; }
        accm.x += bf_lo(v); accm.y += bf_hi(v);
    }
    // drain remaining nodes (incl. zero-degree tail)
    while (ci < 16) FLUSH_NODE();
#undef FLUSH_NODE
}

// ===================== fallback (R2 atomic path) ===========================
__global__ __launch_bounds__(256) void self_kernel(const float* __restrict__ x,
                                                   const float* __restrict__ W,
                                                   const float* __restrict__ b,
                                                   float* __restrict__ out) {
    __shared__ unsigned short xs[64 * D_DIM];
    const int tid = threadIdx.x;
    const int lane = tid & 63, w = tid >> 6;
    const int l15 = lane & 15, lq = lane >> 4;
    short8 wf[2][4];
    load_wfrag(W, w, l15, lq, wf);
    float bias[2];
#pragma unroll
    for (int n = 0; n < 2; ++n) bias[n] = b[(w * 2 + n) * 16 + l15];
    const int rbase = blockIdx.x * 64;
#pragma unroll
    for (int it = 0; it < 8; ++it) {
        int flat = it * 256 + tid;
        int row = flat >> 5, f4 = flat & 31;
        float4 v = *reinterpret_cast<const float4*>(
                       x + (size_t)(rbase + row) * D_DIM + f4 * 4);
        unsigned lo = (unsigned)f2bf(v.x) | ((unsigned)f2bf(v.y) << 16);
        unsigned hi = (unsigned)f2bf(v.z) | ((unsigned)f2bf(v.w) << 16);
        unsigned byte = ((unsigned)(row * 256 + f4 * 8))
                      ^ (((unsigned)(row & 7)) << 4);
        *reinterpret_cast<uint2*>(reinterpret_cast<char*>(xs) + byte) =
            make_uint2(lo, hi);
    }
    __syncthreads();
    f32x4 acc[4][2];
#pragma unroll
    for (int m = 0; m < 4; ++m)
#pragma unroll
        for (int n = 0; n < 2; ++n) acc[m][n] = (f32x4){0.f, 0.f, 0.f, 0.f};
    mfma_tile(xs, wf, l15, lq, acc);
#pragma unroll
    for (int m = 0; m < 4; ++m)
#pragma unroll
        for (int reg = 0; reg < 4; ++reg) {
            int row = rbase + m * 16 + lq * 4 + reg;
#pragma unroll
            for (int n = 0; n < 2; ++n) {
                int c = (w * 2 + n) * 16 + l15;
                out[(size_t)row * D_DIM + c] = acc[m][n][reg] + bias[n];
            }
        }
}

__global__ __launch_bounds__(256) void edge_kernel(const float* __restrict__ x,
                                                   const float* __restrict__ W,
                                                   const float* __restrict__ b,
                                                   const int* __restrict__ dep,
                                                   const int* __restrict__ gov,
                                                   float* __restrict__ out,
                                                   int eg, int blocksPerRel) {
    __shared__ unsigned short xs[64 * D_DIM];
    __shared__ int sidx[CPB][64];
    __shared__ int didx[CPB][64];
    const int tid = threadIdx.x;
    const int lane = tid & 63, w = tid >> 6;
    const int l15 = lane & 15, lq = lane >> 4;
    const int bid = blockIdx.x;
    const int vr = bid / blocksPerRel;
    const int blk = bid % blocksPerRel;
    const int r = vr & 31;
    const bool fwd = (vr < 32);
    const int* __restrict__ srcI = fwd ? gov : dep;
    const int* __restrict__ dstI = fwd ? dep : gov;
    const int ebase0 = r * eg + blk * CPB * 64;
    if (tid < CPB * 64) {
        int c = tid >> 6, t = tid & 63;
        sidx[c][t] = srcI[ebase0 + c * 64 + t];
        didx[c][t] = dstI[ebase0 + c * 64 + t];
    }
    short8 wf[2][4];
    load_wfrag(W + (size_t)(2 + vr) * D_DIM * D_DIM, w, l15, lq, wf);
    float bias[2];
#pragma unroll
    for (int n = 0; n < 2; ++n)
        bias[n] = b[(size_t)(2 + vr) * D_DIM + (w * 2 + n) * 16 + l15];
    __syncthreads();
#pragma unroll
    for (int ch = 0; ch < CPB; ++ch) {
#pragma unroll
        for (int it = 0; it < 8; ++it) {
            int flat = it * 256 + tid;
            int row = flat >> 5, f4 = flat & 31;
            float4 v = *reinterpret_cast<const float4*>(
                           x + (size_t)sidx[ch][row] * D_DIM + f4 * 4);
            unsigned lo = (unsigned)f2bf(v.x) | ((unsigned)f2bf(v.y) << 16);
            unsigned hi = (unsigned)f2bf(v.z) | ((unsigned)f2bf(v.w) << 16);
            unsigned byte = ((unsigned)(row * 256 + f4 * 8))
                          ^ (((unsigned)(row & 7)) << 4);
            *reinterpret_cast<uint2*>(reinterpret_cast<char*>(xs) + byte) =
                make_uint2(lo, hi);
        }
        __syncthreads();
        f32x4 acc[4][2];
#pragma unroll
        for (int m = 0; m < 4; ++m)
#pragma unroll
            for (int n = 0; n < 2; ++n) acc[m][n] = (f32x4){0.f, 0.f, 0.f, 0.f};
        mfma_tile(xs, wf, l15, lq, acc);
#pragma unroll
        for (int m = 0; m < 4; ++m)
#pragma unroll
            for (int reg = 0; reg < 4; ++reg) {
                int erow = m * 16 + lq * 4 + reg;
                int dst = didx[ch][erow];
#pragma unroll
                for (int n = 0; n < 2; ++n) {
                    int c = (w * 2 + n) * 16 + l15;
                    unsafeAtomicAdd(&out[(size_t)dst * D_DIM + c],
                                    acc[m][n][reg] + bias[n]);
                }
            }
        __syncthreads();
    }
}

__global__ void relu_kernel(float* __restrict__ o, int n4) {
    int i = blockIdx.x * blockDim.x + threadIdx.x;
    int stride = gridDim.x * blockDim.x;
    float4* p = reinterpret_cast<float4*>(o);
    for (; i < n4; i += stride) {
        float4 v = p[i];
        v.x = fmaxf(v.x, 0.f); v.y = fmaxf(v.y, 0.f);
        v.z = fmaxf(v.z, 0.f); v.w = fmaxf(v.w, 0.f);
        p[i] = v;
    }
}

// ===========================================================================
extern "C" void kernel_launch(void* const* d_in, const int* in_sizes, int n_in,
                              void* d_out, int out_size, void* d_ws, size_t ws_size,
                              hipStream_t stream) {
    const float* x   = (const float*)d_in[0];
    const float* W   = (const float*)d_in[1];
    const float* b   = (const float*)d_in[2];
    const int*   dep = (const int*)d_in[3];
    const int*   gov = (const int*)d_in[4];
    float* out = (float*)d_out;

    const int N  = in_sizes[0] / D_DIM;   // 262144
    const int E  = in_sizes[3];           // 262144
    const int eg = E / L_REL;             // 8192

    const size_t msgBytes = (size_t)2 * E * 64 * sizeof(unsigned);  // 134.2 MB
    const size_t need = msgBytes + (size_t)(3 * N + 256) * 4 + 4096;

    if (ws_size >= need) {
        char* basep = (char*)d_ws;
        unsigned* msg = (unsigned*)basep;
        int* deg = (int*)(basep + msgBytes);   // [N]
        int* off = deg + (size_t)N;            // [N]
        int* cur = off + (size_t)N;            // [N]
        int* partials = cur + (size_t)N;       // [256]

        hipMemsetAsync(deg, 0, (size_t)N * sizeof(int), stream);
        hist_kernel<<<512, 256, 0, stream>>>(dep, gov, deg, E);
        scanA_kernel<<<N / 1024, 256, 0, stream>>>(deg, off, partials);
        scanB_kernel<<<1, 256, 0, stream>>>(partials);
        scanC_kernel<<<N / 1024, 256, 0, stream>>>(off, cur, partials);

        const int blocksPerRel = eg / 64 / CPB;   // 64
        msg_kernel<<<64 * blocksPerRel, 256, 0, stream>>>(x, W, b, dep, gov,
                                                          cur, msg, eg,
                                                          blocksPerRel);
        agg_kernel<<<N / 64, 256, 0, stream>>>(x, W, b, off, deg, msg, out);
    } else {
        // fallback: atomic scatter path
        self_kernel<<<N / 64, 256, 0, stream>>>(x, W, b, out);
        const int blocksPerRel = eg / 64 / CPB;
        edge_kernel<<<64 * blocksPerRel, 256, 0, stream>>>(x, W, b, dep, gov, out,
                                                           eg, blocksPerRel);
        relu_kernel<<<2048, 256, 0, stream>>>(out, out_size / 4);
    }
}

// Round 7
// 212.576 us; speedup vs baseline: 1.1454x; 1.1454x over previous
//
#include <hip/hip_runtime.h>
#include <hip/hip_bf16.h>
#include <stdint.h>

#define D_DIM 128
#define L_REL 32
#define MSG_LDW 132   // ushort stride, bf16 tiles (264B rows)

typedef __attribute__((ext_vector_type(8))) short short8;   // 8 bf16 = 4 VGPR
typedef __attribute__((ext_vector_type(4))) float f32x4;    // MFMA accumulator

__device__ __forceinline__ unsigned short f2bf(float f) {
    union { float f; unsigned u; } v; v.f = f;
    unsigned r = v.u + 0x7FFFu + ((v.u >> 16) & 1u);   // round-to-nearest-even
    return (unsigned short)(r >> 16);
}
__device__ __forceinline__ float bf_lo(unsigned m) { return __uint_as_float(m << 16); }
__device__ __forceinline__ float bf_hi(unsigned m) { return __uint_as_float(m & 0xffff0000u); }

// B-operand fragment: lane holds W[k][c] for c = tile*16 + (lane&15),
// k = kk*32 + (lane>>4)*8 + j (j contiguous).
__device__ __forceinline__ void load_wfrag(const float* __restrict__ Wr,
                                           int w, int l15, int lq,
                                           short8 wf[2][4]) {
#pragma unroll
    for (int n = 0; n < 2; ++n) {
        int c = (w * 2 + n) * 16 + l15;
#pragma unroll
        for (int kk = 0; kk < 4; ++kk) {
            int kb = kk * 32 + lq * 8;
            short8 f;
#pragma unroll
            for (int j = 0; j < 8; ++j)
                f[j] = (short)f2bf(Wr[(size_t)(kb + j) * D_DIM + c]);
            wf[n][kk] = f;
        }
    }
}

// 64x128 (rows x k, bf16, XOR-swizzled) LDS tile  @  W(128x128) -> acc 64x128
__device__ __forceinline__ void mfma_tile(const unsigned short* xs,
                                          const short8 wf[2][4],
                                          int l15, int lq, f32x4 acc[4][2]) {
#pragma unroll
    for (int kk = 0; kk < 4; ++kk) {
        short8 a[4];
#pragma unroll
        for (int m = 0; m < 4; ++m) {
            int row = m * 16 + l15;
            unsigned byte = ((unsigned)(row * 256 + (kk * 32 + lq * 8) * 2))
                          ^ (((unsigned)(row & 7)) << 4);
            a[m] = *reinterpret_cast<const short8*>(
                       reinterpret_cast<const char*>(xs) + byte);
        }
#pragma unroll
        for (int m = 0; m < 4; ++m)
#pragma unroll
            for (int n = 0; n < 2; ++n)
                acc[m][n] = __builtin_amdgcn_mfma_f32_16x16x32_bf16(
                                a[m], wf[n][kk], acc[m][n], 0, 0, 0);
    }
}

// ===================== combined CSR build (deg = in-deg fwd+rev) ===========
__global__ void hist_kernel(const int* __restrict__ dep, const int* __restrict__ gov,
                            int* __restrict__ deg, int E) {
    int i = blockIdx.x * blockDim.x + threadIdx.x;
    int stride = gridDim.x * blockDim.x;
    for (; i < E; i += stride) {
        atomicAdd(&deg[dep[i]], 1);
        atomicAdd(&deg[gov[i]], 1);
    }
}

__global__ __launch_bounds__(256) void scanA_kernel(const int* __restrict__ deg,
                                                    int* __restrict__ off,
                                                    int* __restrict__ partials) {
    __shared__ int ls[256];
    const int tid = threadIdx.x;
    const int gi = blockIdx.x * 256 + tid;
    int4 v = ((const int4*)deg)[gi];
    int s = v.x + v.y + v.z + v.w;
    ls[tid] = s;
    __syncthreads();
    for (int o = 1; o < 256; o <<= 1) {
        int t = (tid >= o) ? ls[tid - o] : 0;
        __syncthreads();
        ls[tid] += t;
        __syncthreads();
    }
    int e0 = ls[tid] - s;
    int4 e; e.x = e0; e.y = e0 + v.x; e.z = e.y + v.y; e.w = e.z + v.z;
    ((int4*)off)[gi] = e;
    if (tid == 255) partials[blockIdx.x] = ls[255];
}

__global__ __launch_bounds__(256) void scanB_kernel(int* __restrict__ partials) {
    __shared__ int ls[256];
    const int tid = threadIdx.x;
    int v = partials[tid];
    ls[tid] = v;
    __syncthreads();
    for (int o = 1; o < 256; o <<= 1) {
        int t = (tid >= o) ? ls[tid - o] : 0;
        __syncthreads();
        ls[tid] += t;
        __syncthreads();
    }
    partials[tid] = ls[tid] - v;   // exclusive
}

__global__ __launch_bounds__(256) void scanC_kernel(int* __restrict__ off,
                                                    int* __restrict__ cur,
                                                    const int* __restrict__ partials) {
    const int p = partials[blockIdx.x];
    const int gi = blockIdx.x * 256 + threadIdx.x;
    int4 v = ((int4*)off)[gi];
    v.x += p; v.y += p; v.z += p; v.w += p;
    ((int4*)off)[gi] = v;
    ((int4*)cur)[gi] = v;
}

// ====================== messages -> dst-sorted bf16 buffer ==================
#define CPB 4
__global__ __launch_bounds__(256) void msg_kernel(const float* __restrict__ x,
                                                  const float* __restrict__ W,
                                                  const float* __restrict__ b,
                                                  const int* __restrict__ dep,
                                                  const int* __restrict__ gov,
                                                  int* __restrict__ cur,
                                                  unsigned* __restrict__ msg,
                                                  int eg, int blocksPerRel) {
    // union: xs (64x128 bf16 swizzled, 16KB) / tr (64x132 ushort, 16.9KB)
    __shared__ __align__(16) char smem[64 * MSG_LDW * 2];
    unsigned short* xs = (unsigned short*)smem;
    unsigned short* tr = (unsigned short*)smem;
    __shared__ int sidx[CPB][64];
    __shared__ int didx[CPB][64];
    __shared__ int pos[64];

    const int tid = threadIdx.x;
    const int lane = tid & 63, w = tid >> 6;
    const int l15 = lane & 15, lq = lane >> 4;

    const int bid = blockIdx.x;
    const int vr = bid / blocksPerRel;
    const int blk = bid % blocksPerRel;
    const int r = vr & 31;
    const bool fwd = (vr < 32);
    const int* __restrict__ srcI = fwd ? gov : dep;
    const int* __restrict__ dstI = fwd ? dep : gov;

    const int ebase0 = r * eg + blk * CPB * 64;
    {
        int c = tid >> 6, t = tid & 63;   // 256 threads cover 4x64
        sidx[c][t] = srcI[ebase0 + c * 64 + t];
        didx[c][t] = dstI[ebase0 + c * 64 + t];
    }

    short8 wf[2][4];
    load_wfrag(W + (size_t)(2 + vr) * D_DIM * D_DIM, w, l15, lq, wf);
    float bias[2];
#pragma unroll
    for (int n = 0; n < 2; ++n)
        bias[n] = b[(size_t)(2 + vr) * D_DIM + (w * 2 + n) * 16 + l15];

    __syncthreads();

    for (int ch = 0; ch < CPB; ++ch) {
        // gather 64 source rows -> bf16 swizzled LDS
#pragma unroll
        for (int it = 0; it < 8; ++it) {
            int flat = it * 256 + tid;
            int row = flat >> 5, f4 = flat & 31;
            float4 v = *reinterpret_cast<const float4*>(
                           x + (size_t)sidx[ch][row] * D_DIM + f4 * 4);
            unsigned lo = (unsigned)f2bf(v.x) | ((unsigned)f2bf(v.y) << 16);
            unsigned hi = (unsigned)f2bf(v.z) | ((unsigned)f2bf(v.w) << 16);
            unsigned byte = ((unsigned)(row * 256 + f4 * 8))
                          ^ (((unsigned)(row & 7)) << 4);
            *reinterpret_cast<uint2*>(reinterpret_cast<char*>(xs) + byte) =
                make_uint2(lo, hi);
        }
        __syncthreads();

        f32x4 acc[4][2];
#pragma unroll
        for (int m = 0; m < 4; ++m)
#pragma unroll
            for (int n = 0; n < 2; ++n) acc[m][n] = (f32x4){0.f, 0.f, 0.f, 0.f};
        mfma_tile(xs, wf, l15, lq, acc);

        // reserve dst-sorted slots: ONE int atomic per edge (combined cur)
        if (tid < 64) pos[tid] = atomicAdd(&cur[didx[ch][tid]], 1);
        __syncthreads();   // all xs reads done; pos visible

        // transpose acc (+bias) -> bf16 LDS tile [64][MSG_LDW]
#pragma unroll
        for (int m = 0; m < 4; ++m)
#pragma unroll
            for (int reg = 0; reg < 4; ++reg) {
                int row = m * 16 + lq * 4 + reg;
#pragma unroll
                for (int n = 0; n < 2; ++n)
                    tr[row * MSG_LDW + w * 32 + n * 16 + l15] =
                        f2bf(acc[m][n][reg] + bias[n]);
            }
        __syncthreads();

        // wave-per-row: read packed dword (2 cols), store 256B row at slot
#pragma unroll
        for (int i = 0; i < 16; ++i) {
            int r0 = w * 16 + i;
            unsigned dw = *reinterpret_cast<const unsigned*>(
                              reinterpret_cast<const char*>(tr)
                              + r0 * MSG_LDW * 2 + lane * 4);
            msg[(size_t)pos[r0] * 64 + lane] = dw;
        }
        __syncthreads();
    }
}

// ====== fused: self-GEMM + monotone streaming msg reduce + bias + ReLU =====
// Self tile stored as bf16 (unioned with xs) -> 17KB LDS -> 8 blocks/CU.
// Stream 8 rows in flight; msgs accumulate in f32 registers.
__global__ __launch_bounds__(256) void agg_kernel(const float* __restrict__ x,
                                                  const float* __restrict__ W,
                                                  const float* __restrict__ b,
                                                  const int* __restrict__ off,
                                                  const int* __restrict__ deg,
                                                  const unsigned* __restrict__ msg,
                                                  float* __restrict__ out) {
    // union: xs (16KB) -> self tile bf16 (64 x MSG_LDW, 16.9KB)
    __shared__ __align__(16) char smem[64 * MSG_LDW * 2];
    unsigned short* xs = (unsigned short*)smem;
    unsigned short* st = (unsigned short*)smem;
    __shared__ int offs[64 + 1];   // offs[64] = end of block's row range

    const int tid = threadIdx.x;
    const int lane = tid & 63, w = tid >> 6;
    const int l15 = lane & 15, lq = lane >> 4;
    const int base = blockIdx.x * 64;

    if (tid < 64) offs[tid] = off[base + tid];
    if (tid == 64) offs[64] = off[base + 63] + deg[base + 63];

    short8 wf[2][4];
    load_wfrag(W, w, l15, lq, wf);          // W[SELF]
    float bias[2];
#pragma unroll
    for (int n = 0; n < 2; ++n) bias[n] = b[(w * 2 + n) * 16 + l15];

    // stage 64 consecutive node rows
#pragma unroll
    for (int it = 0; it < 8; ++it) {
        int flat = it * 256 + tid;
        int row = flat >> 5, f4 = flat & 31;
        float4 v = *reinterpret_cast<const float4*>(
                       x + (size_t)(base + row) * D_DIM + f4 * 4);
        unsigned lo = (unsigned)f2bf(v.x) | ((unsigned)f2bf(v.y) << 16);
        unsigned hi = (unsigned)f2bf(v.z) | ((unsigned)f2bf(v.w) << 16);
        unsigned byte = ((unsigned)(row * 256 + f4 * 8))
                      ^ (((unsigned)(row & 7)) << 4);
        *reinterpret_cast<uint2*>(reinterpret_cast<char*>(xs) + byte) =
            make_uint2(lo, hi);
    }
    __syncthreads();

    f32x4 acc[4][2];
#pragma unroll
    for (int m = 0; m < 4; ++m)
#pragma unroll
        for (int n = 0; n < 2; ++n) acc[m][n] = (f32x4){0.f, 0.f, 0.f, 0.f};
    mfma_tile(xs, wf, l15, lq, acc);
    __syncthreads();   // xs consumed; LDS becomes bf16 self tile

    // seed self tile with self-term (+bias), bf16
#pragma unroll
    for (int m = 0; m < 4; ++m)
#pragma unroll
        for (int reg = 0; reg < 4; ++reg) {
            int row = m * 16 + lq * 4 + reg;
#pragma unroll
            for (int n = 0; n < 2; ++n)
                st[row * MSG_LDW + w * 32 + n * 16 + l15] =
                    f2bf(acc[m][n][reg] + bias[n]);
        }
    __syncthreads();

    // ---- monotone stream over this wave's contiguous rows ----
    const int nfirst = w * 16;
    int ci = 0;                      // node cursor within wave's 16
    float2 accm = make_float2(0.f, 0.f);

#define FLUSH_NODE()                                                          \
    do {                                                                      \
        const unsigned sv = *reinterpret_cast<const unsigned*>(               \
            reinterpret_cast<const char*>(st)                                 \
            + (nfirst + ci) * MSG_LDW * 2 + lane * 4);                        \
        float2 so;                                                            \
        so.x = fmaxf(bf_lo(sv) + accm.x, 0.f);                                \
        so.y = fmaxf(bf_hi(sv) + accm.y, 0.f);                                \
        *reinterpret_cast<float2*>(                                           \
            out + (size_t)(base + nfirst + ci) * D_DIM + lane * 2) = so;      \
        accm.x = 0.f; accm.y = 0.f;                                           \
        ++ci;                                                                 \
    } while (0)

    const int s0 = offs[nfirst];
    const int s1 = offs[nfirst + 16];
    int nb = offs[nfirst + 1];
    int j = s0;
    const unsigned* mp = msg + (size_t)j * 64 + lane;

    // 8 rows in flight
    for (; j + 8 <= s1; j += 8, mp += 512) {
        unsigned v[8];
#pragma unroll
        for (int k = 0; k < 8; ++k) v[k] = mp[k * 64];
#pragma unroll
        for (int k = 0; k < 8; ++k) {
            int jj = j + k;
            while (jj >= nb) { FLUSH_NODE(); nb = offs[nfirst + ci + 1]; }
            accm.x += bf_lo(v[k]); accm.y += bf_hi(v[k]);
        }
    }
    for (; j < s1; ++j, mp += 64) {
        unsigned v = mp[0];
        while (j >= nb) { FLUSH_NODE(); nb = offs[nfirst + ci + 1]; }
        accm.x += bf_lo(v); accm.y += bf_hi(v);
    }
    // drain remaining nodes (incl. zero-degree tail)
    while (ci < 16) FLUSH_NODE();
#undef FLUSH_NODE
}

// ===================== fallback (R2 atomic path) ===========================
__global__ __launch_bounds__(256) void self_kernel(const float* __restrict__ x,
                                                   const float* __restrict__ W,
                                                   const float* __restrict__ b,
                                                   float* __restrict__ out) {
    __shared__ unsigned short xs[64 * D_DIM];
    const int tid = threadIdx.x;
    const int lane = tid & 63, w = tid >> 6;
    const int l15 = lane & 15, lq = lane >> 4;
    short8 wf[2][4];
    load_wfrag(W, w, l15, lq, wf);
    float bias[2];
#pragma unroll
    for (int n = 0; n < 2; ++n) bias[n] = b[(w * 2 + n) * 16 + l15];
    const int rbase = blockIdx.x * 64;
#pragma unroll
    for (int it = 0; it < 8; ++it) {
        int flat = it * 256 + tid;
        int row = flat >> 5, f4 = flat & 31;
        float4 v = *reinterpret_cast<const float4*>(
                       x + (size_t)(rbase + row) * D_DIM + f4 * 4);
        unsigned lo = (unsigned)f2bf(v.x) | ((unsigned)f2bf(v.y) << 16);
        unsigned hi = (unsigned)f2bf(v.z) | ((unsigned)f2bf(v.w) << 16);
        unsigned byte = ((unsigned)(row * 256 + f4 * 8))
                      ^ (((unsigned)(row & 7)) << 4);
        *reinterpret_cast<uint2*>(reinterpret_cast<char*>(xs) + byte) =
            make_uint2(lo, hi);
    }
    __syncthreads();
    f32x4 acc[4][2];
#pragma unroll
    for (int m = 0; m < 4; ++m)
#pragma unroll
        for (int n = 0; n < 2; ++n) acc[m][n] = (f32x4){0.f, 0.f, 0.f, 0.f};
    mfma_tile(xs, wf, l15, lq, acc);
#pragma unroll
    for (int m = 0; m < 4; ++m)
#pragma unroll
        for (int reg = 0; reg < 4; ++reg) {
            int row = rbase + m * 16 + lq * 4 + reg;
#pragma unroll
            for (int n = 0; n < 2; ++n) {
                int c = (w * 2 + n) * 16 + l15;
                out[(size_t)row * D_DIM + c] = acc[m][n][reg] + bias[n];
            }
        }
}

__global__ __launch_bounds__(256) void edge_kernel(const float* __restrict__ x,
                                                   const float* __restrict__ W,
                                                   const float* __restrict__ b,
                                                   const int* __restrict__ dep,
                                                   const int* __restrict__ gov,
                                                   float* __restrict__ out,
                                                   int eg, int blocksPerRel) {
    __shared__ unsigned short xs[64 * D_DIM];
    __shared__ int sidx[CPB][64];
    __shared__ int didx[CPB][64];
    const int tid = threadIdx.x;
    const int lane = tid & 63, w = tid >> 6;
    const int l15 = lane & 15, lq = lane >> 4;
    const int bid = blockIdx.x;
    const int vr = bid / blocksPerRel;
    const int blk = bid % blocksPerRel;
    const int r = vr & 31;
    const bool fwd = (vr < 32);
    const int* __restrict__ srcI = fwd ? gov : dep;
    const int* __restrict__ dstI = fwd ? dep : gov;
    const int ebase0 = r * eg + blk * CPB * 64;
    {
        int c = tid >> 6, t = tid & 63;
        sidx[c][t] = srcI[ebase0 + c * 64 + t];
        didx[c][t] = dstI[ebase0 + c * 64 + t];
    }
    short8 wf[2][4];
    load_wfrag(W + (size_t)(2 + vr) * D_DIM * D_DIM, w, l15, lq, wf);
    float bias[2];
#pragma unroll
    for (int n = 0; n < 2; ++n)
        bias[n] = b[(size_t)(2 + vr) * D_DIM + (w * 2 + n) * 16 + l15];
    __syncthreads();
#pragma unroll
    for (int ch = 0; ch < CPB; ++ch) {
#pragma unroll
        for (int it = 0; it < 8; ++it) {
            int flat = it * 256 + tid;
            int row = flat >> 5, f4 = flat & 31;
            float4 v = *reinterpret_cast<const float4*>(
                           x + (size_t)sidx[ch][row] * D_DIM + f4 * 4);
            unsigned lo = (unsigned)f2bf(v.x) | ((unsigned)f2bf(v.y) << 16);
            unsigned hi = (unsigned)f2bf(v.z) | ((unsigned)f2bf(v.w) << 16);
            unsigned byte = ((unsigned)(row * 256 + f4 * 8))
                          ^ (((unsigned)(row & 7)) << 4);
            *reinterpret_cast<uint2*>(reinterpret_cast<char*>(xs) + byte) =
                make_uint2(lo, hi);
        }
        __syncthreads();
        f32x4 acc[4][2];
#pragma unroll
        for (int m = 0; m < 4; ++m)
#pragma unroll
            for (int n = 0; n < 2; ++n) acc[m][n] = (f32x4){0.f, 0.f, 0.f, 0.f};
        mfma_tile(xs, wf, l15, lq, acc);
#pragma unroll
        for (int m = 0; m < 4; ++m)
#pragma unroll
            for (int reg = 0; reg < 4; ++reg) {
                int erow = m * 16 + lq * 4 + reg;
                int dst = didx[ch][erow];
#pragma unroll
                for (int n = 0; n < 2; ++n) {
                    int c = (w * 2 + n) * 16 + l15;
                    unsafeAtomicAdd(&out[(size_t)dst * D_DIM + c],
                                    acc[m][n][reg] + bias[n]);
                }
            }
        __syncthreads();
    }
}

__global__ void relu_kernel(float* __restrict__ o, int n4) {
    int i = blockIdx.x * blockDim.x + threadIdx.x;
    int stride = gridDim.x * blockDim.x;
    float4* p = reinterpret_cast<float4*>(o);
    for (; i < n4; i += stride) {
        float4 v = p[i];
        v.x = fmaxf(v.x, 0.f); v.y = fmaxf(v.y, 0.f);
        v.z = fmaxf(v.z, 0.f); v.w = fmaxf(v.w, 0.f);
        p[i] = v;
    }
}

// ===========================================================================
extern "C" void kernel_launch(void* const* d_in, const int* in_sizes, int n_in,
                              void* d_out, int out_size, void* d_ws, size_t ws_size,
                              hipStream_t stream) {
    const float* x   = (const float*)d_in[0];
    const float* W   = (const float*)d_in[1];
    const float* b   = (const float*)d_in[2];
    const int*   dep = (const int*)d_in[3];
    const int*   gov = (const int*)d_in[4];
    float* out = (float*)d_out;

    const int N  = in_sizes[0] / D_DIM;   // 262144
    const int E  = in_sizes[3];           // 262144
    const int eg = E / L_REL;             // 8192

    const size_t msgBytes = (size_t)2 * E * 64 * sizeof(unsigned);  // 134.2 MB
    const size_t need = msgBytes + (size_t)(3 * N + 256) * 4 + 4096;

    if (ws_size >= need) {
        char* basep = (char*)d_ws;
        unsigned* msg = (unsigned*)basep;
        int* deg = (int*)(basep + msgBytes);   // [N]
        int* off = deg + (size_t)N;            // [N]
        int* cur = off + (size_t)N;            // [N]
        int* partials = cur + (size_t)N;       // [256]

        hipMemsetAsync(deg, 0, (size_t)N * sizeof(int), stream);
        hist_kernel<<<512, 256, 0, stream>>>(dep, gov, deg, E);
        scanA_kernel<<<N / 1024, 256, 0, stream>>>(deg, off, partials);
        scanB_kernel<<<1, 256, 0, stream>>>(partials);
        scanC_kernel<<<N / 1024, 256, 0, stream>>>(off, cur, partials);

        const int blocksPerRel = eg / 64 / CPB;   // 32
        msg_kernel<<<64 * blocksPerRel, 256, 0, stream>>>(x, W, b, dep, gov,
                                                          cur, msg, eg,
                                                          blocksPerRel);
        agg_kernel<<<N / 64, 256, 0, stream>>>(x, W, b, off, deg, msg, out);
    } else {
        // fallback: atomic scatter path
        self_kernel<<<N / 64, 256, 0, stream>>>(x, W, b, out);
        const int blocksPerRel = eg / 64 / CPB;
        edge_kernel<<<64 * blocksPerRel, 256, 0, stream>>>(x, W, b, dep, gov, out,
                                                           eg, blocksPerRel);
        relu_kernel<<<2048, 256, 0, stream>>>(out, out_size / 4);
    }
}